// Round 11
// baseline (178.810 us; speedup 1.0000x reference)
//
#include <hip/hip_runtime.h>
#include <hip/hip_fp16.h>

// CapsuleLayer dynamic routing — round 15: 2x occupancy via split-b + L2-resident W.
// Round-14 post-mortem: spill finally dead (VGPR=72, WRITE=160KB=output) but
// rounds sit at 47.5us with VALUBusy 32% / HBM 4.5% / occupancy 28% — nothing
// saturated -> latency-bound at 12 waves/CU (grid 256 = 1 block/CU hard cap),
// aggravated by per-XCD working set (Wc 2.95 + X 1.2 MB) > 4MB XCD-L2
// (FETCH=16.6MB re-fetched EVERY round).
// Fixes, keeping the proven spill-free body:
//  * split each b across 2 blocks (18 Gp each, 9 waves x 2 gl, TPB=576),
//    grid (2,256) = 512 blocks -> 2 blocks/CU = 18 waves/CU. Rounds write
//    PARTIAL s (plain stores); next round's staging folds sum+squash; tiny
//    final-squash kernel after RD2. No atomics.
//  * linear block id = half + 2b with XCD = id%8 -> even XCDs serve half 0,
//    odd serve half 1 -> per-XCD W share 1.47MB + X 1.2MB < 4MB = L2-resident
//    across rounds (FETCH should collapse for RD1/2).
//  * biasP padded to 12 floats/row (wprep-side) -> 3 float4 loads per i
//    instead of 10 scalar uncoalesced loads.

#define IC 1152
#define IE 8
#define NC 10
#define DV 16
#define NB 256
#define NW (IC * NC * IE * DV)  // 1,474,560
#define SOUT (NC * DV)          // 160
#define NWAVE 9
#define TPB (NWAVE * 64)        // 576
#define NGPW 2                  // Gp groups per wave (18 per half = 9*2)
#define HGP 18                  // Gp groups per half-block

typedef _Float16 h2 __attribute__((ext_vector_type(2)));
union WChunk { int4 v; h2 p[4]; _Float16 h[8]; };
union XFrag { int4 v; h2 p[4]; };

#if defined(__has_builtin) && __has_builtin(__builtin_amdgcn_fdot2)
__device__ inline float fdot2(h2 a, h2 b, float c) {
    return __builtin_amdgcn_fdot2(a, b, c, false);
}
#else
__device__ inline float fdot2(h2 a, h2 b, float c) {
    return fmaf((float)a.x, (float)b.x, fmaf((float)a.y, (float)b.y, c));
}
#endif

// W fp32 [i][j][e][d] -> fp16 chunks Wc[((Gp*10+j)*8+k)*64 + lane], where
// lane = h*32+r, i = Gp*32+r, d = h*8+k; chunk holds e=0..7 halves of W[i,j,:,d].
__global__ void wprep_kernel(const float* __restrict__ W, int4* __restrict__ Wc) {
    const int t = blockIdx.x * blockDim.x + threadIdx.x;
    if (t >= NW / 8) return;
    const int lane = t & 63;
    const int h = lane >> 5, r = lane & 31;
    const int k = (t >> 6) & 7;
    const int r2 = t >> 9;  // Gp*10 + j
    const int j = r2 % NC, Gp = r2 / NC;
    const int i = Gp * 32 + r;
    const int d = h * 8 + k;
    const float* src = W + ((size_t)(i * NC + j) * IE) * DV + d;  // e-stride DV
    WChunk c;
#pragma unroll
    for (int e = 0; e < IE; ++e) c.h[e] = (_Float16)src[(size_t)e * DV];
    Wc[t] = c.v;
}

// bias [i*10+j] -> biasP [i*12+j] (48B padded rows, float4-loadable)
__global__ void bprep_kernel(const float* __restrict__ bias, float* __restrict__ biasP) {
    const int t = blockIdx.x * blockDim.x + threadIdx.x;  // < IC*12
    const int i = t / 12, j = t - i * 12;
    biasP[t] = (j < NC) ? bias[i * NC + j] : 0.f;
}

// Splitting butterfly over the 32 r-lanes of one d-half: s8[8] -> one value
// per 4-lane group, accumulated into slab8[dl].
__device__ inline void butterfly_acc(const float* s8, int r, float* slab8) {
    float t4[4];
#pragma unroll
    for (int d = 0; d < 4; ++d) {
        const bool hi = (r & 16);
        const float mine = hi ? s8[d + 4] : s8[d];
        const float send = hi ? s8[d] : s8[d + 4];
        t4[d] = mine + __shfl_xor(send, 16);
    }
    float t2[2];
#pragma unroll
    for (int d = 0; d < 2; ++d) {
        const bool hi = (r & 8);
        const float mine = hi ? t4[d + 2] : t4[d];
        const float send = hi ? t4[d] : t4[d + 2];
        t2[d] = mine + __shfl_xor(send, 8);
    }
    float t1;
    {
        const bool hi = (r & 4);
        const float mine = hi ? t2[1] : t2[0];
        const float send = hi ? t2[0] : t2[1];
        t1 = mine + __shfl_xor(send, 4);
    }
    t1 += __shfl_xor(t1, 2);
    t1 += __shfl_xor(t1, 1);
    if ((r & 3) == 0) {
        const int dl = (r >> 2) & 7;  // bit map: r4->d2, r3->d1, r2->d0
        slab8[dl] += t1;
    }
}

// One routing round over half the i-rows (host-side rd loop = LICM barrier).
// blockIdx = (half, b). Staging folds the previous round's partial-s pair into
// v (sum + squash); end writes this block's partial s (plain stores).
// RD=0: c = softmax(bias).            -> spOut
// RD=1: v1 = squash(spIn); logits v1. -> spOut; half0 writes v1g.
// RD=2: vsum = v1g + squash(spIn); logits vsum. -> spOut (final squash kernel follows).
template <int RD>
__global__ __launch_bounds__(TPB) void round_caps(
    const float* __restrict__ X,      // [B, IC, IE] fp32
    const int4* __restrict__ Wc,      // coalesced fp16 W (see wprep)
    const float* __restrict__ biasP,  // [IC*12] padded
    const float* __restrict__ spIn,   // [2*B*160] partial s of prev round
    float* __restrict__ v1g,          // [B*160] v1 (written RD1, read RD2)
    float* __restrict__ spOut)        // [2*B*160] this round's partial s
{
    __shared__ float s_part[NWAVE * SOUT];      // per-wave exclusive slabs (5.8KB)
    __shared__ __align__(16) h2 v2s[SOUT / 2];  // running v packed for fdot2

    const int half = blockIdx.x;  // 0..1
    const int b = blockIdx.y;     // 0..255
    const int tid = threadIdx.x;
    const int w = tid >> 6;  // wave 0..8
    const int g = tid & 63;
    const int h = g >> 5;    // d-half: d = h*8 + k
    const int r = g & 31;    // row within 32-row group

    // ---- staging: fold prev partials -> v; pack v2s ----
    if constexpr (RD > 0) {
        if (tid < SOUT) {
            float sv = spIn[(size_t)b * SOUT + tid] +
                       spIn[((size_t)NB + b) * SOUT + tid];
            float s2 = sv * sv;
#pragma unroll
            for (int mk = 8; mk >= 1; mk >>= 1) s2 += __shfl_xor(s2, mk, 16);
            float vv = sqrtf(s2) / (1.f + s2) * sv;
            if constexpr (RD == 2) {
                vv += v1g[(size_t)b * SOUT + tid];  // vsum = v1 + v2
            } else {
                if (half == 0) v1g[(size_t)b * SOUT + tid] = vv;
            }
            const float oth = __shfl_xor(vv, 1);
            if (!(tid & 1)) v2s[tid >> 1] = h2{(_Float16)vv, (_Float16)oth};
        }
    }
    // zero own slab (wave-private)
    for (int idx = g; idx < SOUT; idx += 64) s_part[w * SOUT + idx] = 0.f;
    if constexpr (RD > 0) __syncthreads();  // v2s ready

#pragma unroll
    for (int gl = 0; gl < NGPW; ++gl) {
        const int Gp = half * HGP + NGPW * w + gl;
        const int i = Gp * 32 + r;

        // ---- X row packed to h2 ----
        XFrag xu;
        {
            const float4* xr = (const float4*)(X + ((size_t)b * IC + i) * IE);
            const float4 x0 = xr[0], x1 = xr[1];
            xu.p[0] = h2{(_Float16)x0.x, (_Float16)x0.y};
            xu.p[1] = h2{(_Float16)x0.z, (_Float16)x0.w};
            xu.p[2] = h2{(_Float16)x1.x, (_Float16)x1.y};
            xu.p[3] = h2{(_Float16)x1.z, (_Float16)x1.w};
        }
        // ---- bias row via 3 x float4 ----
        float bl[12];
        {
            const float4* bp4 = (const float4*)(biasP + (size_t)i * 12);
            const float4 b0 = bp4[0], b1 = bp4[1], b2 = bp4[2];
            bl[0] = b0.x; bl[1] = b0.y; bl[2] = b0.z; bl[3] = b0.w;
            bl[4] = b1.x; bl[5] = b1.y; bl[6] = b1.z; bl[7] = b1.w;
            bl[8] = b2.x; bl[9] = b2.y; bl[10] = b2.z; bl[11] = b2.w;
        }
        const int4* wpg = Wc + (size_t)(Gp * NC) * 512 + g;
        float* slab = &s_part[w * SOUT + h * 8];  // + j*DV per j

        if constexpr (RD == 0) {
            // c = softmax(bias) first (hat-independent); hat transient per j.
            float cj[NC];
            float Z = 0.f;
#pragma unroll
            for (int j = 0; j < NC; ++j) {
                const float e = __expf(bl[j]);
                cj[j] = e;
                Z += e;
            }
            const float rz = 1.f / Z;
#pragma unroll
            for (int j = 0; j < NC; ++j) cj[j] *= rz;

#pragma unroll
            for (int j = 0; j < NC; ++j) {
                const int4* wp = wpg + j * 512;
                float s8[8];
#pragma unroll
                for (int kp = 0; kp < 4; ++kp) {
                    WChunk w0, w1;
                    w0.v = wp[(2 * kp) * 64];
                    w1.v = wp[(2 * kp + 1) * 64];
                    float a0 = 0.f, a1 = 0.f;
#pragma unroll
                    for (int q = 0; q < 4; ++q) {
                        a0 = fdot2(xu.p[q], w0.p[q], a0);
                        a1 = fdot2(xu.p[q], w1.p[q], a1);
                    }
                    s8[2 * kp] = cj[j] * a0;
                    s8[2 * kp + 1] = cj[j] * a1;
                }
                butterfly_acc(s8, r, slab + j * DV);
            }
        } else {
            // pass A: hat2 resident (40 h2), logits fused into the hat loop.
            h2 hat2[NC][4];
            float cj[NC];
            float Z = 0.f;
#pragma unroll
            for (int j = 0; j < NC; ++j) {
                const int4* wp = wpg + j * 512;
#pragma unroll
                for (int kp = 0; kp < 4; ++kp) {
                    WChunk w0, w1;
                    w0.v = wp[(2 * kp) * 64];
                    w1.v = wp[(2 * kp + 1) * 64];
                    float a0 = 0.f, a1 = 0.f;
#pragma unroll
                    for (int q = 0; q < 4; ++q) {
                        a0 = fdot2(xu.p[q], w0.p[q], a0);
                        a1 = fdot2(xu.p[q], w1.p[q], a1);
                    }
                    hat2[j][kp] = h2{(_Float16)a0, (_Float16)a1};
                }
                XFrag vv;
                vv.v = *(const int4*)(v2s + (j * 8 + h * 4));
                float ah = 0.f;
#pragma unroll
                for (int q = 0; q < 4; ++q) ah = fdot2(hat2[j][q], vv.p[q], ah);
                const float lt = bl[j] + ah + __shfl_xor(ah, 32);
                const float e = __expf(lt);
                cj[j] = e;
                Z += e;
            }
            const float rz = 1.f / Z;

            // pass B: weighted sum from resident hat2 (1/Z folded in).
#pragma unroll
            for (int j = 0; j < NC; ++j) {
                const float cn = cj[j] * rz;
                float s8[8];
#pragma unroll
                for (int q = 0; q < 4; ++q) {
                    s8[2 * q]     = cn * (float)hat2[j][q].x;
                    s8[2 * q + 1] = cn * (float)hat2[j][q].y;
                }
                butterfly_acc(s8, r, slab + j * DV);
            }
        }
    }
    __syncthreads();

    // ---- reduce slabs -> this block's partial s (plain stores) ----
    if (tid < SOUT) {
        float sv = 0.f;
#pragma unroll
        for (int ww = 0; ww < NWAVE; ++ww) sv += s_part[ww * SOUT + tid];
        spOut[((size_t)half * NB + b) * SOUT + tid] = sv;
    }
}

// out[b] = squash(sp[0][b] + sp[1][b])
__global__ __launch_bounds__(192) void final_squash(const float* __restrict__ sp,
                                                    float* __restrict__ out) {
    const int b = blockIdx.x, t = threadIdx.x;
    if (t < SOUT) {
        float sv = sp[(size_t)b * SOUT + t] + sp[((size_t)NB + b) * SOUT + t];
        float s2 = sv * sv;
#pragma unroll
        for (int mk = 8; mk >= 1; mk >>= 1) s2 += __shfl_xor(s2, mk, 16);
        out[(size_t)b * SOUT + t] = sqrtf(s2) / (1.f + s2) * sv;
    }
}

extern "C" void kernel_launch(void* const* d_in, const int* in_sizes, int n_in,
                              void* d_out, int out_size, void* d_ws, size_t ws_size,
                              hipStream_t stream) {
    const float* X = (const float*)d_in[0];     // [256,1152,8]
    const float* W = (const float*)d_in[1];     // [1152,10,8,16]
    const float* bias = (const float*)d_in[2];  // [1,1152,10]
    float* out = (float*)d_out;

    // ws: Wc (2.95MB) | biasP (55KB) | v1g (160KB) | spA | spB | spC (327KB each)
    int4* Wc = (int4*)d_ws;
    float* biasP = (float*)(Wc + NW / 8);
    float* v1g = biasP + IC * 12;
    float* spA = v1g + (size_t)NB * SOUT;
    float* spB = spA + 2ull * NB * SOUT;
    float* spC = spB + 2ull * NB * SOUT;

    wprep_kernel<<<dim3(720), dim3(256), 0, stream>>>(W, Wc);
    bprep_kernel<<<dim3(54), dim3(256), 0, stream>>>(bias, biasP);

    dim3 grid(2, NB);  // linear id = half + 2b -> XCD = id%8 pins halves to XCDs
    round_caps<0><<<grid, TPB, 0, stream>>>(X, Wc, biasP, nullptr, nullptr, spA);
    round_caps<1><<<grid, TPB, 0, stream>>>(X, Wc, biasP, spA, v1g, spB);
    round_caps<2><<<grid, TPB, 0, stream>>>(X, Wc, biasP, spB, v1g, spC);
    final_squash<<<dim3(NB), dim3(192), 0, stream>>>(spC, out);
}

// Round 12
// 152.854 us; speedup vs baseline: 1.1698x; 1.1698x over previous
//
#include <hip/hip_runtime.h>
#include <hip/hip_fp16.h>

// CapsuleLayer dynamic routing — round 16: LDS-staged W, 8 batch elements/block.
// r14/r15 post-mortem: rounds pinned at 47.5us at BOTH 12 and 18 waves/CU,
// with FETCH collapsing and VALUBusy stuck at 33% -> the invariant is per-CU:
// each CU pulled W (2.95MB) from L2 once per round with ZERO reuse (W >> L1).
// 2.95MB / 47.5us = 62 GB/s = the per-CU L2 return rate. More waves just queue
// on the same port. Fix: stage a Gp-slice of W (80KB) into LDS once per block
// and share it across 8 batch elements (1 wave each): per-CU L2 W-traffic
// drops 8x (360KB, ~6us); the re-reads hit LDS (~614 GB/s/CU). Partial s per
// (Gp,b) -> global; tiny reduce kernel per round does 36-way sum + squash +
// packs v. Grid (36,32)=1152 blocks, 80KB LDS -> 2 blocks/CU = 16 waves/CU.
// Body = the r14 spill-free body (VGPR 72) with ds_read instead of global.

#define IC 1152
#define IE 8
#define NC 10
#define DV 16
#define NB 256
#define NW (IC * NC * IE * DV)  // 1,474,560
#define SOUT (NC * DV)          // 160
#define GPB (IC / 32)           // 36 row-groups
#define NBB 8                   // batch elements per block = waves per block
#define TPB (NBB * 64)          // 512
#define WSLOT (NC * 8 * 64)     // 5120 int4 = 80 KB per Gp slice

typedef _Float16 h2 __attribute__((ext_vector_type(2)));
union WChunk { int4 v; h2 p[4]; _Float16 h[8]; };
union XFrag { int4 v; h2 p[4]; };

#if defined(__has_builtin) && __has_builtin(__builtin_amdgcn_fdot2)
__device__ inline float fdot2(h2 a, h2 b, float c) {
    return __builtin_amdgcn_fdot2(a, b, c, false);
}
#else
__device__ inline float fdot2(h2 a, h2 b, float c) {
    return fmaf((float)a.x, (float)b.x, fmaf((float)a.y, (float)b.y, c));
}
#endif

// W fp32 [i][j][e][d] -> fp16 chunks Wc[((Gp*10+j)*8+k)*64 + lane], where
// lane = h*32+r, i = Gp*32+r, d = h*8+k; chunk holds e=0..7 halves of W[i,j,:,d].
__global__ void wprep_kernel(const float* __restrict__ W, int4* __restrict__ Wc) {
    const int t = blockIdx.x * blockDim.x + threadIdx.x;
    if (t >= NW / 8) return;
    const int lane = t & 63;
    const int h = lane >> 5, r = lane & 31;
    const int k = (t >> 6) & 7;
    const int r2 = t >> 9;  // Gp*10 + j
    const int j = r2 % NC, Gp = r2 / NC;
    const int i = Gp * 32 + r;
    const int d = h * 8 + k;
    const float* src = W + ((size_t)(i * NC + j) * IE) * DV + d;  // e-stride DV
    WChunk c;
#pragma unroll
    for (int e = 0; e < IE; ++e) c.h[e] = (_Float16)src[(size_t)e * DV];
    Wc[t] = c.v;
}

// Splitting butterfly over the 32 r-lanes of one d-half: s8[8] -> one value
// per 4-lane group; lanes (r&3)==0 store to dst8[dl]. Exclusive (Gp,b) slice
// per wave -> plain stores.
__device__ inline void butterfly_store(const float* s8, int r, float* dst8) {
    float t4[4];
#pragma unroll
    for (int d = 0; d < 4; ++d) {
        const bool hi = (r & 16);
        const float mine = hi ? s8[d + 4] : s8[d];
        const float send = hi ? s8[d] : s8[d + 4];
        t4[d] = mine + __shfl_xor(send, 16);
    }
    float t2[2];
#pragma unroll
    for (int d = 0; d < 2; ++d) {
        const bool hi = (r & 8);
        const float mine = hi ? t4[d + 2] : t4[d];
        const float send = hi ? t4[d] : t4[d + 2];
        t2[d] = mine + __shfl_xor(send, 8);
    }
    float t1;
    {
        const bool hi = (r & 4);
        const float mine = hi ? t2[1] : t2[0];
        const float send = hi ? t2[0] : t2[1];
        t1 = mine + __shfl_xor(send, 4);
    }
    t1 += __shfl_xor(t1, 2);
    t1 += __shfl_xor(t1, 1);
    if ((r & 3) == 0) {
        const int dl = (r >> 2) & 7;  // bit map: r4->d2, r3->d1, r2->d0
        dst8[dl] = t1;
    }
}

// One routing round. Block = (Gp, b-group of 8); wave w owns b = bg*8+w and
// the whole Gp (lane g = h*32+r -> row i=Gp*32+r, d-half h). W slice in LDS,
// shared by the 8 waves. Thread-local softmax over j. Writes partial s for
// (Gp, b) — complete over this Gp's 32 rows.
template <int RD>
__global__ __launch_bounds__(TPB) void round_caps(
    const float* __restrict__ X,     // [B, IC, IE] fp32
    const int4* __restrict__ Wc,     // coalesced fp16 W (see wprep)
    const float* __restrict__ bias,  // [IC*NC] fp32
    const h2* __restrict__ vredH,    // [B*80] packed v (RD>0)
    float* __restrict__ sp)          // [GPB*NB*SOUT] partial s
{
    __shared__ __align__(16) int4 Ws[WSLOT];  // 80 KB -> 2 blocks/CU

    const int Gp = blockIdx.x;  // 0..35
    const int bg = blockIdx.y;  // 0..31
    const int tid = threadIdx.x;
    const int w = tid >> 6;  // wave 0..7
    const int g = tid & 63;
    const int h = g >> 5;    // d-half: d = h*8 + k
    const int r = g & 31;    // row within the 32-row group

    // ---- stage W Gp-slice global->LDS (coalesced, conflict-free) ----
    {
        const int4* src = Wc + (size_t)Gp * WSLOT;
#pragma unroll
        for (int k = 0; k < WSLOT / TPB; ++k)  // 10 iters
            Ws[tid + k * TPB] = src[tid + k * TPB];
    }

    const int b = bg * NBB + w;
    const int i = Gp * 32 + r;

    // ---- X row packed to h2 (issue before the barrier to overlap) ----
    XFrag xu;
    {
        const float4* xr = (const float4*)(X + ((size_t)b * IC + i) * IE);
        const float4 x0 = xr[0], x1 = xr[1];
        xu.p[0] = h2{(_Float16)x0.x, (_Float16)x0.y};
        xu.p[1] = h2{(_Float16)x0.z, (_Float16)x0.w};
        xu.p[2] = h2{(_Float16)x1.x, (_Float16)x1.y};
        xu.p[3] = h2{(_Float16)x1.z, (_Float16)x1.w};
    }

    float cj[NC];
    float Z = 0.f;
    if constexpr (RD == 0) {
        // c = softmax(bias) — b-independent, hoisted before the barrier
#pragma unroll
        for (int j = 0; j < NC; ++j) {
            const float e = __expf(bias[i * NC + j]);
            cj[j] = e;
            Z += e;
        }
        const float rz = 1.f / Z;
#pragma unroll
        for (int j = 0; j < NC; ++j) cj[j] *= rz;
    }

    __syncthreads();  // Ws ready

    float* spb = sp + ((size_t)Gp * NB + b) * SOUT;

    if constexpr (RD == 0) {
        // hat transient per j, immediate butterfly (low regs)
#pragma unroll
        for (int j = 0; j < NC; ++j) {
            const int4* wp = Ws + j * 512 + g;
            float s8[8];
#pragma unroll
            for (int kp = 0; kp < 4; ++kp) {
                WChunk w0, w1;
                w0.v = wp[(2 * kp) * 64];
                w1.v = wp[(2 * kp + 1) * 64];
                float a0 = 0.f, a1 = 0.f;
#pragma unroll
                for (int q = 0; q < 4; ++q) {
                    a0 = fdot2(xu.p[q], w0.p[q], a0);
                    a1 = fdot2(xu.p[q], w1.p[q], a1);
                }
                s8[2 * kp] = cj[j] * a0;
                s8[2 * kp + 1] = cj[j] * a1;
            }
            butterfly_store(s8, r, spb + j * DV + h * 8);
        }
    } else {
        // pass A: hat2 resident (40 h2), logits fused into the hat loop
        h2 hat2[NC][4];
#pragma unroll
        for (int j = 0; j < NC; ++j) {
            const int4* wp = Ws + j * 512 + g;
#pragma unroll
            for (int kp = 0; kp < 4; ++kp) {
                WChunk w0, w1;
                w0.v = wp[(2 * kp) * 64];
                w1.v = wp[(2 * kp + 1) * 64];
                float a0 = 0.f, a1 = 0.f;
#pragma unroll
                for (int q = 0; q < 4; ++q) {
                    a0 = fdot2(xu.p[q], w0.p[q], a0);
                    a1 = fdot2(xu.p[q], w1.p[q], a1);
                }
                hat2[j][kp] = h2{(_Float16)a0, (_Float16)a1};
            }
            XFrag vv;
            vv.v = *(const int4*)(vredH + (size_t)b * (SOUT / 2) + j * 8 + h * 4);
            float ah = 0.f;
#pragma unroll
            for (int q = 0; q < 4; ++q) ah = fdot2(hat2[j][q], vv.p[q], ah);
            const float lt = bias[i * NC + j] + ah + __shfl_xor(ah, 32);
            const float e = __expf(lt);
            cj[j] = e;
            Z += e;
        }
        const float rz = 1.f / Z;

        // pass B: weighted sum from resident hat2 (1/Z folded in)
#pragma unroll
        for (int j = 0; j < NC; ++j) {
            const float cn = cj[j] * rz;
            float s8[8];
#pragma unroll
            for (int q = 0; q < 4; ++q) {
                s8[2 * q]     = cn * (float)hat2[j][q].x;
                s8[2 * q + 1] = cn * (float)hat2[j][q].y;
            }
            butterfly_store(s8, r, spb + j * DV + h * 8);
        }
    }
}

// Per-round reduce: v = squash(sum over 36 Gp partials) (+ vprev for P2).
// P1: writes voutF (f32, for P2's add) + voutH (packed h2 for the next round).
// P2: writes voutH only (vsum packed). P3: writes final output.
template <int P>
__global__ __launch_bounds__(192) void reduce_caps(
    const float* __restrict__ sp,      // [GPB*NB*SOUT]
    const float* __restrict__ vprevF,  // P==2
    float* __restrict__ voutF,         // P==1
    h2* __restrict__ voutH,            // P<=2
    float* __restrict__ out)           // P==3
{
    const int b = blockIdx.x, t = threadIdx.x;
    if (t >= SOUT) return;
    float sv = 0.f;
#pragma unroll
    for (int gq = 0; gq < GPB; ++gq) sv += sp[((size_t)gq * NB + b) * SOUT + t];
    float s2 = sv * sv;
#pragma unroll
    for (int mk = 8; mk >= 1; mk >>= 1) s2 += __shfl_xor(s2, mk, 16);
    float vv = sqrtf(s2) / (1.f + s2) * sv;
    if constexpr (P == 2) vv += vprevF[(size_t)b * SOUT + t];  // vsum = v1 + v2
    if constexpr (P == 3) {
        out[(size_t)b * SOUT + t] = vv;
        return;
    } else {
        if constexpr (P == 1) voutF[(size_t)b * SOUT + t] = vv;
        const float oth = __shfl_xor(vv, 1);
        if (!(t & 1))
            voutH[(size_t)b * (SOUT / 2) + (t >> 1)] = h2{(_Float16)vv, (_Float16)oth};
    }
}

extern "C" void kernel_launch(void* const* d_in, const int* in_sizes, int n_in,
                              void* d_out, int out_size, void* d_ws, size_t ws_size,
                              hipStream_t stream) {
    const float* X = (const float*)d_in[0];     // [256,1152,8]
    const float* W = (const float*)d_in[1];     // [1152,10,8,16]
    const float* bias = (const float*)d_in[2];  // [1,1152,10]
    float* out = (float*)d_out;

    // ws: Wc 2.95MB | spA/spB/spC 5.9MB each | v1F 160KB | vH1/vH2 80KB each
    int4* Wc = (int4*)d_ws;
    float* spA = (float*)(Wc + NW / 8);
    float* spB = spA + (size_t)GPB * NB * SOUT;
    float* spC = spB + (size_t)GPB * NB * SOUT;
    float* v1F = spC + (size_t)GPB * NB * SOUT;
    h2* vH1 = (h2*)(v1F + (size_t)NB * SOUT);
    h2* vH2 = vH1 + (size_t)NB * (SOUT / 2);

    wprep_kernel<<<dim3(720), dim3(256), 0, stream>>>(W, Wc);

    dim3 rg(GPB, NB / NBB);  // (36, 32)
    round_caps<0><<<rg, TPB, 0, stream>>>(X, Wc, bias, nullptr, spA);
    reduce_caps<1><<<dim3(NB), dim3(192), 0, stream>>>(spA, nullptr, v1F, vH1, nullptr);
    round_caps<1><<<rg, TPB, 0, stream>>>(X, Wc, bias, vH1, spB);
    reduce_caps<2><<<dim3(NB), dim3(192), 0, stream>>>(spB, v1F, nullptr, vH2, nullptr);
    round_caps<2><<<rg, TPB, 0, stream>>>(X, Wc, bias, vH2, spC);
    reduce_caps<3><<<dim3(NB), dim3(192), 0, stream>>>(spC, nullptr, nullptr, nullptr, out);
}